// Round 2
// baseline (237.404 us; speedup 1.0000x reference)
//
#include <hip/hip_runtime.h>

// Attention block: B=8, C=D=128, H=W=64, N=4096.
// out = x + Wo·(softmax(Qᵀ K /√C) @ V) + bo, Q/K/V = 1x1-conv projections.
//
// attn: 32x32x16 MFMA, S = K·Q -> D[j][q]; j-order permuted so exp2(S) regs ARE
// the PV B-operand (V staged col-permuted in LDS). K+V tiles in LDS, double-
// buffered (round-12: one __syncthreads per j-iter); raw v_exp via
// __builtin_amdgcn_exp2f; s_setprio(1) around MFMA clusters (T5).
// Round-13: outp_kernel DELETED — fused into attn via split-K "last block
// combines" pattern: both split-blocks write o_part/l_part (unchanged),
// __threadfence + per-(b,i0) atomicAdd counter (zeroed by qkv each iteration,
// graph-replay safe); second arriver re-reads both partials (own is L2-hot),
// normalizes, stages Wo in the dead K/V LDS, Wo GEMM + bias + residual -> out.
// Math is byte-identical to the old outp kernel (same bf16 partials from
// global, same sum order). Saves a launch + o_part round-trip latency + 512
// cold-block prologues. LDS 70.2 KB -> still 2 blocks/CU.
// Split-j x2: grid = 512 blocks = exactly one co-resident cohort (2/CU).
// __launch_bounds__(256,2): acc AGPRs count against the unified file (round-8:
// (256,3) -> VGPR cap 128 -> scratch spill).
// qkv: fused q/k/v; x staged once; weights fp32->bf16 inline into padded LDS;
// also zeroes the rendezvous counters (runs strictly before attn).
// Round-11: hipLaunchCooperativeKernel never executed (poison output) — normal
// launches + device-scope atomics it is.

typedef float  f32x4  __attribute__((ext_vector_type(4)));
typedef float  f32x16 __attribute__((ext_vector_type(16)));
typedef short  s16x8  __attribute__((ext_vector_type(8)));
typedef short  s16x4  __attribute__((ext_vector_type(4)));
typedef unsigned uint4v __attribute__((ext_vector_type(4)));

#define MFMA16(A, Bb, Cc) __builtin_amdgcn_mfma_f32_16x16x32_bf16(A, Bb, Cc, 0, 0, 0)
#define MFMA32(A, Bb, Cc) __builtin_amdgcn_mfma_f32_32x32x16_bf16(A, Bb, Cc, 0, 0, 0)

#define BATCH 8
#define DIM   128
#define NN    4096
#define NSPLIT 2
#define JCHUNK (NN / NSPLIT)
#define NT    (JCHUNK / 64)
// 1/sqrt(128) * log2(e)  (q-scale so attn can use exp2)
#define Q_SCALE 0.12751649736784776f

#if __has_builtin(__builtin_amdgcn_exp2f)
#define EXP2(x) __builtin_amdgcn_exp2f(x)
#else
#define EXP2(x) exp2f(x)
#endif

__device__ __forceinline__ unsigned short f2bf(float f) {
  union { float f; unsigned u; } v; v.f = f;
  unsigned r = v.u + 0x7FFFu + ((v.u >> 16) & 1u);  // RNE
  return (unsigned short)(r >> 16);
}
__device__ __forceinline__ float bf2f(unsigned short h) {
  union { unsigned u; float f; } v; v.u = ((unsigned)h) << 16;
  return v.f;
}
__device__ __forceinline__ s16x8 cvt8(const float* src) {
  float4 a = *(const float4*)src;
  float4 b = *(const float4*)(src + 4);
  s16x8 f;
  f[0] = (short)f2bf(a.x); f[1] = (short)f2bf(a.y);
  f[2] = (short)f2bf(a.z); f[3] = (short)f2bf(a.w);
  f[4] = (short)f2bf(b.x); f[5] = (short)f2bf(b.y);
  f[6] = (short)f2bf(b.z); f[7] = (short)f2bf(b.w);
  return f;
}

// ---------------------------------------------------------------- QKV projection
// Grid (64 i-tiles, 8 batches). Block 256; each wave 16 i, 128 d, all 3 heads.
// x staged [c][i] fp32 pad 68; weights converted+staged per-z in padded LDS.
__global__ __launch_bounds__(256) void qkv_kernel(
    const float* __restrict__ x,
    const float* __restrict__ wq, const float* __restrict__ wk,
    const float* __restrict__ wv,
    const float* __restrict__ bq, const float* __restrict__ bk,
    const float* __restrict__ bv,
    unsigned short* __restrict__ qt,          // [B][N][D]
    unsigned short* __restrict__ kt,          // [B][N][D]
    unsigned short* __restrict__ vv,          // [B][D][N]
    int* __restrict__ cnt) {                  // [B*32] rendezvous counters
  __shared__ float xs[DIM * 68];              // 34.8 KB
  __shared__ unsigned short wls[DIM * 136];   // 34.8 KB (one z at a time)
  const int b = blockIdx.y;
  const int i0 = blockIdx.x * 64;
  const int tid = threadIdx.x;

  // zero the attn rendezvous counters (qkv completes before attn starts)
  if (blockIdx.x == 0 && blockIdx.y == 0 && tid < 256) cnt[tid] = 0;

  for (int idx = tid; idx < 2048; idx += 256) {
    int c = idx >> 4, i4 = idx & 15;
    float4 val = *(const float4*)(x + ((size_t)(b * DIM + c)) * NN + i0 + i4 * 4);
    xs[c * 68 + i4 * 4 + 0] = val.x;
    xs[c * 68 + i4 * 4 + 1] = val.y;
    xs[c * 68 + i4 * 4 + 2] = val.z;
    xs[c * 68 + i4 * 4 + 3] = val.w;
  }
  __syncthreads();

  const int w = tid >> 6, lane = tid & 63, quad = lane >> 4, l15 = lane & 15;
  const int iloc = w * 16 + l15;

  // B-frags from x tile (once, reused by all 3 heads)
  s16x8 bfrag[4];
#pragma unroll
  for (int ch = 0; ch < 4; ch++) {
    s16x8 f;
#pragma unroll
    for (int jj = 0; jj < 8; jj++) {
      int c = ch * 32 + quad * 8 + jj;
      f[jj] = (short)f2bf(xs[c * 68 + iloc]);
    }
    bfrag[ch] = f;
  }

  const int i = i0 + iloc;
  const int wr = tid >> 4, wc = tid & 15;   // weight staging coords

  for (int z = 0; z < 3; z++) {
    __syncthreads();  // prior z's wls reads done
    const float* wsrc = (z == 0) ? wq : (z == 1) ? wk : wv;
#pragma unroll
    for (int it = 0; it < 8; it++) {
      const int row = it * 16 + wr;
      *(s16x8*)(&wls[row * 136 + wc * 8]) = cvt8(wsrc + row * DIM + wc * 8);
    }
    __syncthreads();

    const float* bias = (z == 0) ? bq : (z == 1) ? bk : bv;
    const float sc = (z == 0) ? Q_SCALE : 1.0f;

    for (int t = 0; t < 8; t++) {
      const int dl = t * 16;
      f32x4 acc = {0.f, 0.f, 0.f, 0.f};
#pragma unroll
      for (int ch = 0; ch < 4; ch++) {
        s16x8 af = *(const s16x8*)(&wls[(dl + l15) * 136 + ch * 32 + quad * 8]);
        acc = MFMA16(af, bfrag[ch], acc);
      }
      if (z < 2) {
        unsigned short* dstb = (z == 0) ? qt : kt;
        s16x4 o;
#pragma unroll
        for (int r = 0; r < 4; r++) {
          int d = dl + quad * 4 + r;
          o[r] = (short)f2bf((acc[r] + bias[d]) * sc);
        }
        *(s16x4*)(dstb + ((size_t)b * NN + i) * DIM + dl + quad * 4) = o;
      } else {
#pragma unroll
        for (int r = 0; r < 4; r++) {
          int d = dl + quad * 4 + r;
          vv[((size_t)b * DIM + d) * NN + i] = f2bf(acc[r] + bias[d]);
        }
      }
    }
  }
}

// ---------------------------------------------------------------- flash attention
// Grid (32 q-tiles of 128, 8 batches, 2 j-splits) = 512 blocks. 4 waves x 32 q.
// Epilogue: split-K rendezvous; last arriver combines splits + Wo GEMM + residual.
__global__ __launch_bounds__(256, 2) void attn_kernel(
    const unsigned short* __restrict__ qt,
    const unsigned short* __restrict__ kt,
    const unsigned short* __restrict__ vv,
    const float* __restrict__ x,
    const float* __restrict__ wo,
    const float* __restrict__ bo,
    unsigned short* __restrict__ o_part,   // [S][B][N][D] bf16, un-normalized
    float* __restrict__ l_part,            // [S][B][N]
    int* __restrict__ cnt,                 // [B*32]
    float* __restrict__ out) {
  // 70.2 KB: main loop K/V dbuf in [0,32768) shorts; winner epilogue reuses as
  // wls [0,17408) + ytile [17408,34816) + invl. 2 blocks/CU either way.
  __shared__ unsigned short sh[35072];
  __shared__ int s_old;
  const int b = blockIdx.y;
  const int i0 = blockIdx.x * 128;
  const int split = blockIdx.z;
  const int jbase = split * JCHUNK;
  const int tid = threadIdx.x;
  const int w = tid >> 6, lane = tid & 63;
  const int l31 = lane & 31, h = lane >> 5;

  const unsigned short* kb = kt + (size_t)b * NN * DIM;
  const unsigned short* vb = vv + (size_t)b * DIM * NN;

  // persistent Q B-frags: B[k=d][n=q], lane n=l31, k = 16*kc + 8*h + i
  s16x8 qfrag[8];
  {
    const unsigned short* qrow =
        qt + ((size_t)b * NN + i0 + w * 32 + l31) * DIM + h * 8;
#pragma unroll
    for (int kc = 0; kc < 8; kc++)
      qfrag[kc] = *(const s16x8*)(qrow + kc * 16);
  }

  f32x16 acc[4];
#pragma unroll
  for (int mt = 0; mt < 4; mt++)
#pragma unroll
    for (int e = 0; e < 16; e++) acc[mt][e] = 0.f;
  float l_acc = 0.f;

  // staging thread coordinates (iter-invariant)
  const int kr = tid >> 4, kc_ = tid & 15;   // K: row kr + it*16, chunk kc_
  const int vr = tid >> 3, vc = tid & 7;     // V: row vr + it*32, 8-col group vc
  const int vch0 = (vc & 1) ? (vc - 1) : vc; // V column permutation
  const int vch1 = (vc & 1) ? vc : (vc + 1);
  const int vpos = (vc & 1) * 4;

  s16x8 kpre[4], vpre[4];

  // ---- prologue: tile 0 -> regs -> buf0; tile 1 -> regs
#pragma unroll
  for (int it = 0; it < 4; it++) {
    kpre[it] = *(const s16x8*)(kb + (size_t)(jbase + it * 16 + kr) * DIM + kc_ * 8);
    vpre[it] = *(const s16x8*)(vb + (size_t)(it * 32 + vr) * NN + jbase + vc * 8);
  }
#pragma unroll
  for (int it = 0; it < 4; it++) {
    const int r = it * 16 + kr;
    *(s16x8*)(sh + (((r << 4) + (kc_ ^ (r & 15))) << 3)) = kpre[it];
    const int r2 = it * 32 + vr;
    union { s16x8 v8; s16x4 v4[2]; } sp; sp.v8 = vpre[it];
    *(s16x4*)(sh + 8192 + (((r2 << 3) + (vch0 ^ (r2 & 7))) << 3) + vpos) = sp.v4[0];
    *(s16x4*)(sh + 8192 + (((r2 << 3) + (vch1 ^ (r2 & 7))) << 3) + vpos) = sp.v4[1];
  }
#pragma unroll
  for (int it = 0; it < 4; it++) {
    kpre[it] = *(const s16x8*)(kb + (size_t)(jbase + 64 + it * 16 + kr) * DIM + kc_ * 8);
    vpre[it] = *(const s16x8*)(vb + (size_t)(it * 32 + vr) * NN + jbase + 64 + vc * 8);
  }

  for (int t = 0; t < NT; t++) {
    // single barrier per iter: buf[t&1] (written last iter) is ready, and all
    // waves' reads of buf[(t+1)&1] (= last iter's compute buffer) are done.
    __syncthreads();

    // ---- write prefetched tile t+1 -> other buffer (swizzled; V col-permuted)
    if (t + 1 < NT) {
      unsigned short* wb = sh + ((~t & 1) << 14);
#pragma unroll
      for (int it = 0; it < 4; it++) {
        const int r = it * 16 + kr;
        *(s16x8*)(wb + (((r << 4) + (kc_ ^ (r & 15))) << 3)) = kpre[it];
        const int r2 = it * 32 + vr;
        union { s16x8 v8; s16x4 v4[2]; } sp; sp.v8 = vpre[it];
        *(s16x4*)(wb + 8192 + (((r2 << 3) + (vch0 ^ (r2 & 7))) << 3) + vpos) = sp.v4[0];
        *(s16x4*)(wb + 8192 + (((r2 << 3) + (vch1 ^ (r2 & 7))) << 3) + vpos) = sp.v4[1];
      }
    }

    // ---- prefetch tile t+2 into registers (no barrier dependency)
    if (t + 2 < NT) {
      const int jn = jbase + (t + 2) * 64;
#pragma unroll
      for (int it = 0; it < 4; it++) {
        kpre[it] = *(const s16x8*)(kb + (size_t)(jn + it * 16 + kr) * DIM + kc_ * 8);
        vpre[it] = *(const s16x8*)(vb + (size_t)(it * 32 + vr) * NN + jn + vc * 8);
      }
    }

    const unsigned short* rK = sh + ((t & 1) << 14);
    const unsigned short* rV = rK + 8192;

    // ---- S = K·Q -> D[j][q]; P = exp2(S); PV straight from S registers
#pragma unroll
    for (int jt = 0; jt < 2; jt++) {
      f32x16 S;
#pragma unroll
      for (int e = 0; e < 16; e++) S[e] = 0.f;
      const int j = jt * 32 + l31;
      __builtin_amdgcn_s_setprio(1);
#pragma unroll
      for (int kc = 0; kc < 8; kc++) {
        s16x8 kf = *(const s16x8*)(rK + (((j << 4) + ((2 * kc + h) ^ (j & 15))) << 3));
        S = MFMA32(kf, qfrag[kc], S);
      }
      __builtin_amdgcn_s_setprio(0);
      unsigned pk[8];
#pragma unroll
      for (int p = 0; p < 8; p++) {
        float e0 = EXP2(S[2 * p]), e1 = EXP2(S[2 * p + 1]);
        l_acc += e0 + e1;
        union { float f; unsigned u; } u0, u1; u0.f = e0; u1.f = e1;
        pk[p] = __builtin_amdgcn_perm(u1.u, u0.u, 0x07060302u);  // [bf16(e0),bf16(e1)]
      }
      __builtin_amdgcn_s_setprio(1);
#pragma unroll
      for (int bl = 0; bl < 2; bl++) {
        union { uint4v u; s16x8 v; } pu;
        pu.u[0] = pk[4 * bl + 0]; pu.u[1] = pk[4 * bl + 1];
        pu.u[2] = pk[4 * bl + 2]; pu.u[3] = pk[4 * bl + 3];
        const s16x8 pf = pu.v;
        const int c0 = (jt * 2 + bl) * 2 + h;  // logical V chunk
#pragma unroll
        for (int mt = 0; mt < 4; mt++) {
          const int d = mt * 32 + l31;
          s16x8 vf = *(const s16x8*)(rV + (((d << 3) + (c0 ^ (d & 7))) << 3));
          acc[mt] = MFMA32(vf, pf, acc[mt]);
        }
      }
      __builtin_amdgcn_s_setprio(0);
    }
  }

  const float l_tot = l_acc + __shfl_xor(l_acc, 32, 64);

  // ---- epilogue: transpose O via per-wave LDS slice, coalesced b128 stores
  __syncthreads();  // all waves done reading K/V tiles
  unsigned short* ep = sh + w * 4096;  // 8 KB per wave
#pragma unroll
  for (int mt = 0; mt < 4; mt++)
#pragma unroll
    for (int reg = 0; reg < 16; reg++) {
      int d = mt * 32 + (reg & 3) + 8 * (reg >> 2) + 4 * h;
      int dc = d >> 3;
      ep[(l31 << 7) + ((dc ^ (l31 & 15)) << 3) + (d & 7)] = f2bf(acc[mt][reg]);
    }
  __syncthreads();
#pragma unroll
  for (int it = 0; it < 8; it++) {
    int qr = it * 4 + (lane >> 4), cr = lane & 15;
    s16x8 v = *(const s16x8*)(ep + (qr << 7) + ((cr ^ (qr & 15)) << 3));
    *(s16x8*)(o_part + (((size_t)split * BATCH + b) * NN + i0 + w * 32 + qr) * DIM +
              cr * 8) = v;
  }
  if (lane < 32)
    l_part[((size_t)split * BATCH + b) * NN + i0 + w * 32 + lane] = l_tot;

  // ---- split-K rendezvous: second arriver combines + Wo GEMM + residual ----
  __threadfence();  // release: this block's o_part/l_part visible device-wide
  if (tid == 0) s_old = atomicAdd(&cnt[blockIdx.y * 32 + blockIdx.x], 1);
  __syncthreads();
  if (s_old == 0) return;   // first arriver exits
  __threadfence();          // acquire: drop any stale cached o_part/l_part

  unsigned short* wls   = sh;                    // [128][136] bf16 Wo
  unsigned short* ytile = sh + DIM * 136;        // [128][136] bf16 y
  float* invl = (float*)(sh + 2 * DIM * 136);    // [128]

  const int wr = tid >> 4, wc = tid & 15;
#pragma unroll
  for (int it = 0; it < 8; it++) {
    const int row = it * 16 + wr;
    *(s16x8*)(&wls[row * 136 + wc * 8]) = cvt8(wo + row * DIM + wc * 8);
  }
  if (tid < 128) {
    float l = 0.f;
#pragma unroll
    for (int s = 0; s < NSPLIT; s++)
      l += l_part[((size_t)s * BATCH + b) * NN + i0 + tid];
    invl[tid] = 1.0f / l;
  }
  __syncthreads();

  // phase 1: read both splits' o_part rows (coalesced b128), sum, normalize
#pragma unroll
  for (int k = 0; k < 8; k++) {
    int slot = k * 256 + tid;            // 2048 slots = 128 rows x 16 granules
    int i = slot >> 4, g = slot & 15;
    float o[8] = {0.f, 0.f, 0.f, 0.f, 0.f, 0.f, 0.f, 0.f};
#pragma unroll
    for (int s = 0; s < NSPLIT; s++) {
      s16x8 ov = *(const s16x8*)(o_part +
                                 (((size_t)s * BATCH + b) * NN + i0 + i) * DIM + g * 8);
#pragma unroll
      for (int jj = 0; jj < 8; jj++) o[jj] += bf2f((unsigned short)ov[jj]);
    }
    const float inv = invl[i];
    s16x8 f;
#pragma unroll
    for (int jj = 0; jj < 8; jj++) f[jj] = (short)f2bf(o[jj] * inv);
    *(s16x8*)(&ytile[i * 136 + g * 8]) = f;
  }
  __syncthreads();

  // phase 2: Wo GEMM from LDS A- and B-frags + bias + residual
  const int quad = lane >> 4, l15 = lane & 15;
#pragma unroll
  for (int half = 0; half < 2; half++) {
    const int il = half * 64 + w * 16 + l15;   // local y row
    s16x8 bfr[4];
#pragma unroll
    for (int ch = 0; ch < 4; ch++)
      bfr[ch] = *(const s16x8*)(&ytile[il * 136 + ch * 32 + quad * 8]);
    for (int t = 0; t < 8; t++) {
      f32x4 a4 = {0.f, 0.f, 0.f, 0.f};
#pragma unroll
      for (int ch = 0; ch < 4; ch++) {
        s16x8 af = *(const s16x8*)(&wls[(t * 16 + l15) * 136 + ch * 32 + quad * 8]);
        a4 = MFMA16(af, bfr[ch], a4);
      }
#pragma unroll
      for (int r = 0; r < 4; r++) {
        int d = t * 16 + quad * 4 + r;
        size_t idx = ((size_t)b * DIM + d) * NN + i0 + il;
        out[idx] = x[idx] + a4[r] + bo[d];
      }
    }
  }
}

// ---------------------------------------------------------------- launch
extern "C" void kernel_launch(void* const* d_in, const int* in_sizes, int n_in,
                              void* d_out, int out_size, void* d_ws, size_t ws_size,
                              hipStream_t stream) {
  const float* x  = (const float*)d_in[0];
  const float* wq = (const float*)d_in[1];
  const float* bq = (const float*)d_in[2];
  const float* wk = (const float*)d_in[3];
  const float* bk = (const float*)d_in[4];
  const float* wv = (const float*)d_in[5];
  const float* bv = (const float*)d_in[6];
  const float* wo = (const float*)d_in[7];
  const float* bo = (const float*)d_in[8];
  float* out = (float*)d_out;

  unsigned short* ws  = (unsigned short*)d_ws;
  unsigned short* qt  = ws;                                 // 8 MB
  unsigned short* kt  = qt + (size_t)BATCH * NN * DIM;      // 8 MB
  unsigned short* vv  = kt + (size_t)BATCH * NN * DIM;      // 8 MB
  unsigned short* o_part = vv + (size_t)BATCH * NN * DIM;   // 16 MB (2 splits)
  float* l_part = (float*)(o_part + (size_t)NSPLIT * BATCH * NN * DIM);  // 256 KB
  int* cnt = (int*)(l_part + (size_t)NSPLIT * BATCH * NN);  // 1 KB

  hipLaunchKernelGGL(qkv_kernel, dim3(64, 8), dim3(256), 0, stream,
                     x, wq, wk, wv, bq, bk, bv, qt, kt, vv, cnt);
  hipLaunchKernelGGL(attn_kernel, dim3(32, 8, NSPLIT), dim3(256), 0, stream,
                     qt, kt, vv, x, wo, bo, o_part, l_part, cnt, out);
}

// Round 3
// 201.838 us; speedup vs baseline: 1.1762x; 1.1762x over previous
//
#include <hip/hip_runtime.h>

// Attention block: B=8, C=D=128, H=W=64, N=4096.
// out = x + Wo·(softmax(Qᵀ K /√C) @ V) + bo, Q/K/V = 1x1-conv projections.
//
// Round-14: revert round-13 split-K fusion (rendezvous epilogue ran as a
// low-occupancy cold tail behind device-scope fences: attn 76.6->159 µs).
// Back to 4-kernel pipeline, attacking the qkv/outp overhead instead:
//   wcvt: one tiny kernel converts wq/wk/wv/wo fp32->bf16 ONCE (round-13
//   profile insight: every qkv block redundantly re-converted + re-staged all
//   3 weight matrices through LDS = 38M wasted VALU ops + 6 barriers/block).
//   qkv/outp now load weight A-frags directly from global bf16 (32 KB/matrix,
//   L1-resident after first touch) — no weight LDS, no per-z barriers.
//   Bit-identical numerics (same f2bf values feeding the same MFMAs).
// attn: byte-identical to round-12 (76.6 µs verified): 32x32x16 MFMA,
// S = K·Q -> D[j][q]; exp2(S) regs ARE the PV B-operand (V col-permuted in
// LDS); K/V double-buffered (one __syncthreads/iter); raw v_exp; setprio.
// Split-j x2: grid = 512 blocks = one co-resident cohort (2/CU).
// __launch_bounds__(256,2): acc AGPRs count against the unified file.

typedef float  f32x4  __attribute__((ext_vector_type(4)));
typedef float  f32x16 __attribute__((ext_vector_type(16)));
typedef short  s16x8  __attribute__((ext_vector_type(8)));
typedef short  s16x4  __attribute__((ext_vector_type(4)));
typedef unsigned uint4v __attribute__((ext_vector_type(4)));

#define MFMA16(A, Bb, Cc) __builtin_amdgcn_mfma_f32_16x16x32_bf16(A, Bb, Cc, 0, 0, 0)
#define MFMA32(A, Bb, Cc) __builtin_amdgcn_mfma_f32_32x32x16_bf16(A, Bb, Cc, 0, 0, 0)

#define BATCH 8
#define DIM   128
#define NN    4096
#define NSPLIT 2
#define JCHUNK (NN / NSPLIT)
#define NT    (JCHUNK / 64)
#define WMAT  (DIM * DIM)   // 16384 elements per weight matrix
// 1/sqrt(128) * log2(e)  (q-scale so attn can use exp2)
#define Q_SCALE 0.12751649736784776f

#if __has_builtin(__builtin_amdgcn_exp2f)
#define EXP2(x) __builtin_amdgcn_exp2f(x)
#else
#define EXP2(x) exp2f(x)
#endif

__device__ __forceinline__ unsigned short f2bf(float f) {
  union { float f; unsigned u; } v; v.f = f;
  unsigned r = v.u + 0x7FFFu + ((v.u >> 16) & 1u);  // RNE
  return (unsigned short)(r >> 16);
}
__device__ __forceinline__ float bf2f(unsigned short h) {
  union { unsigned u; float f; } v; v.u = ((unsigned)h) << 16;
  return v.f;
}
__device__ __forceinline__ s16x8 cvt8(const float* src) {
  float4 a = *(const float4*)src;
  float4 b = *(const float4*)(src + 4);
  s16x8 f;
  f[0] = (short)f2bf(a.x); f[1] = (short)f2bf(a.y);
  f[2] = (short)f2bf(a.z); f[3] = (short)f2bf(a.w);
  f[4] = (short)f2bf(b.x); f[5] = (short)f2bf(b.y);
  f[6] = (short)f2bf(b.z); f[7] = (short)f2bf(b.w);
  return f;
}

// ---------------------------------------------------------------- weight convert
// One-shot fp32->bf16 of all 4 weight matrices. Grid (8,4), 256 thr, 8 elem/thr.
__global__ __launch_bounds__(256) void wcvt_kernel(
    const float* __restrict__ wq, const float* __restrict__ wk,
    const float* __restrict__ wv, const float* __restrict__ wo,
    unsigned short* __restrict__ wb) {        // [4][128][128] bf16
  const float* src = (blockIdx.y == 0) ? wq : (blockIdx.y == 1) ? wk
                   : (blockIdx.y == 2) ? wv : wo;
  const int idx = (blockIdx.x * 256 + threadIdx.x) * 8;
  *(s16x8*)(wb + (size_t)blockIdx.y * WMAT + idx) = cvt8(src + idx);
}

// ---------------------------------------------------------------- QKV projection
// Grid (64 i-tiles, 8 batches). Block 256; each wave 16 i, 128 d, all 3 heads.
// x staged [c][i] fp32 pad 68 (one barrier); weight A-frags direct from global
// bf16 (L1-resident, shared by all blocks).
__global__ __launch_bounds__(256) void qkv_kernel(
    const float* __restrict__ x,
    const unsigned short* __restrict__ wb,    // [3][128][128] bf16 (q,k,v)
    const float* __restrict__ bq, const float* __restrict__ bk,
    const float* __restrict__ bv,
    unsigned short* __restrict__ qt,          // [B][N][D]
    unsigned short* __restrict__ kt,          // [B][N][D]
    unsigned short* __restrict__ vv) {        // [B][D][N]
  __shared__ float xs[DIM * 68];              // 34.8 KB
  const int b = blockIdx.y;
  const int i0 = blockIdx.x * 64;
  const int tid = threadIdx.x;

  for (int idx = tid; idx < 2048; idx += 256) {
    int c = idx >> 4, i4 = idx & 15;
    float4 val = *(const float4*)(x + ((size_t)(b * DIM + c)) * NN + i0 + i4 * 4);
    xs[c * 68 + i4 * 4 + 0] = val.x;
    xs[c * 68 + i4 * 4 + 1] = val.y;
    xs[c * 68 + i4 * 4 + 2] = val.z;
    xs[c * 68 + i4 * 4 + 3] = val.w;
  }
  __syncthreads();

  const int w = tid >> 6, lane = tid & 63, quad = lane >> 4, l15 = lane & 15;
  const int iloc = w * 16 + l15;

  // B-frags from x tile (once, reused by all 3 heads)
  s16x8 bfrag[4];
#pragma unroll
  for (int ch = 0; ch < 4; ch++) {
    s16x8 f;
#pragma unroll
    for (int jj = 0; jj < 8; jj++) {
      int c = ch * 32 + quad * 8 + jj;
      f[jj] = (short)f2bf(xs[c * 68 + iloc]);
    }
    bfrag[ch] = f;
  }

  const int i = i0 + iloc;

  for (int z = 0; z < 3; z++) {
    const unsigned short* wz = wb + (size_t)z * WMAT;
    const float* bias = (z == 0) ? bq : (z == 1) ? bk : bv;
    const float sc = (z == 0) ? Q_SCALE : 1.0f;

    for (int t = 0; t < 8; t++) {
      const int dl = t * 16;
      f32x4 acc = {0.f, 0.f, 0.f, 0.f};
#pragma unroll
      for (int ch = 0; ch < 4; ch++) {
        s16x8 af = *(const s16x8*)(wz + (dl + l15) * DIM + ch * 32 + quad * 8);
        acc = MFMA16(af, bfrag[ch], acc);
      }
      if (z < 2) {
        unsigned short* dstb = (z == 0) ? qt : kt;
        s16x4 o;
#pragma unroll
        for (int r = 0; r < 4; r++) {
          int d = dl + quad * 4 + r;
          o[r] = (short)f2bf((acc[r] + bias[d]) * sc);
        }
        *(s16x4*)(dstb + ((size_t)b * NN + i) * DIM + dl + quad * 4) = o;
      } else {
#pragma unroll
        for (int r = 0; r < 4; r++) {
          int d = dl + quad * 4 + r;
          vv[((size_t)b * DIM + d) * NN + i] = f2bf(acc[r] + bias[d]);
        }
      }
    }
  }
}

// ---------------------------------------------------------------- flash attention
// Grid (32 q-tiles of 128, 8 batches, 2 j-splits) = 512 blocks. 4 waves x 32 q.
__global__ __launch_bounds__(256, 2) void attn_kernel(
    const unsigned short* __restrict__ qt,
    const unsigned short* __restrict__ kt,
    const unsigned short* __restrict__ vv,
    unsigned short* __restrict__ o_part,   // [S][B][N][D] bf16, un-normalized
    float* __restrict__ l_part) {          // [S][B][N]
  __shared__ unsigned short sh[32768];     // 64 KB: 2 x (K 16 KB + V 16 KB)
  const int b = blockIdx.y;
  const int i0 = blockIdx.x * 128;
  const int split = blockIdx.z;
  const int jbase = split * JCHUNK;
  const int tid = threadIdx.x;
  const int w = tid >> 6, lane = tid & 63;
  const int l31 = lane & 31, h = lane >> 5;

  const unsigned short* kb = kt + (size_t)b * NN * DIM;
  const unsigned short* vb = vv + (size_t)b * DIM * NN;

  // persistent Q B-frags: B[k=d][n=q], lane n=l31, k = 16*kc + 8*h + i
  s16x8 qfrag[8];
  {
    const unsigned short* qrow =
        qt + ((size_t)b * NN + i0 + w * 32 + l31) * DIM + h * 8;
#pragma unroll
    for (int kc = 0; kc < 8; kc++)
      qfrag[kc] = *(const s16x8*)(qrow + kc * 16);
  }

  f32x16 acc[4];
#pragma unroll
  for (int mt = 0; mt < 4; mt++)
#pragma unroll
    for (int e = 0; e < 16; e++) acc[mt][e] = 0.f;
  float l_acc = 0.f;

  // staging thread coordinates (iter-invariant)
  const int kr = tid >> 4, kc_ = tid & 15;   // K: row kr + it*16, chunk kc_
  const int vr = tid >> 3, vc = tid & 7;     // V: row vr + it*32, 8-col group vc
  const int vch0 = (vc & 1) ? (vc - 1) : vc; // V column permutation
  const int vch1 = (vc & 1) ? vc : (vc + 1);
  const int vpos = (vc & 1) * 4;

  s16x8 kpre[4], vpre[4];

  // ---- prologue: tile 0 -> regs -> buf0; tile 1 -> regs
#pragma unroll
  for (int it = 0; it < 4; it++) {
    kpre[it] = *(const s16x8*)(kb + (size_t)(jbase + it * 16 + kr) * DIM + kc_ * 8);
    vpre[it] = *(const s16x8*)(vb + (size_t)(it * 32 + vr) * NN + jbase + vc * 8);
  }
#pragma unroll
  for (int it = 0; it < 4; it++) {
    const int r = it * 16 + kr;
    *(s16x8*)(sh + (((r << 4) + (kc_ ^ (r & 15))) << 3)) = kpre[it];
    const int r2 = it * 32 + vr;
    union { s16x8 v8; s16x4 v4[2]; } sp; sp.v8 = vpre[it];
    *(s16x4*)(sh + 8192 + (((r2 << 3) + (vch0 ^ (r2 & 7))) << 3) + vpos) = sp.v4[0];
    *(s16x4*)(sh + 8192 + (((r2 << 3) + (vch1 ^ (r2 & 7))) << 3) + vpos) = sp.v4[1];
  }
#pragma unroll
  for (int it = 0; it < 4; it++) {
    kpre[it] = *(const s16x8*)(kb + (size_t)(jbase + 64 + it * 16 + kr) * DIM + kc_ * 8);
    vpre[it] = *(const s16x8*)(vb + (size_t)(it * 32 + vr) * NN + jbase + 64 + vc * 8);
  }

  for (int t = 0; t < NT; t++) {
    // single barrier per iter: buf[t&1] (written last iter) is ready, and all
    // waves' reads of buf[(t+1)&1] (= last iter's compute buffer) are done.
    __syncthreads();

    // ---- write prefetched tile t+1 -> other buffer (swizzled; V col-permuted)
    if (t + 1 < NT) {
      unsigned short* wb2 = sh + ((~t & 1) << 14);
#pragma unroll
      for (int it = 0; it < 4; it++) {
        const int r = it * 16 + kr;
        *(s16x8*)(wb2 + (((r << 4) + (kc_ ^ (r & 15))) << 3)) = kpre[it];
        const int r2 = it * 32 + vr;
        union { s16x8 v8; s16x4 v4[2]; } sp; sp.v8 = vpre[it];
        *(s16x4*)(wb2 + 8192 + (((r2 << 3) + (vch0 ^ (r2 & 7))) << 3) + vpos) = sp.v4[0];
        *(s16x4*)(wb2 + 8192 + (((r2 << 3) + (vch1 ^ (r2 & 7))) << 3) + vpos) = sp.v4[1];
      }
    }

    // ---- prefetch tile t+2 into registers (no barrier dependency)
    if (t + 2 < NT) {
      const int jn = jbase + (t + 2) * 64;
#pragma unroll
      for (int it = 0; it < 4; it++) {
        kpre[it] = *(const s16x8*)(kb + (size_t)(jn + it * 16 + kr) * DIM + kc_ * 8);
        vpre[it] = *(const s16x8*)(vb + (size_t)(it * 32 + vr) * NN + jn + vc * 8);
      }
    }

    const unsigned short* rK = sh + ((t & 1) << 14);
    const unsigned short* rV = rK + 8192;

    // ---- S = K·Q -> D[j][q]; P = exp2(S); PV straight from S registers
#pragma unroll
    for (int jt = 0; jt < 2; jt++) {
      f32x16 S;
#pragma unroll
      for (int e = 0; e < 16; e++) S[e] = 0.f;
      const int j = jt * 32 + l31;
      __builtin_amdgcn_s_setprio(1);
#pragma unroll
      for (int kc = 0; kc < 8; kc++) {
        s16x8 kf = *(const s16x8*)(rK + (((j << 4) + ((2 * kc + h) ^ (j & 15))) << 3));
        S = MFMA32(kf, qfrag[kc], S);
      }
      __builtin_amdgcn_s_setprio(0);
      unsigned pk[8];
#pragma unroll
      for (int p = 0; p < 8; p++) {
        float e0 = EXP2(S[2 * p]), e1 = EXP2(S[2 * p + 1]);
        l_acc += e0 + e1;
        union { float f; unsigned u; } u0, u1; u0.f = e0; u1.f = e1;
        pk[p] = __builtin_amdgcn_perm(u1.u, u0.u, 0x07060302u);  // [bf16(e0),bf16(e1)]
      }
      __builtin_amdgcn_s_setprio(1);
#pragma unroll
      for (int bl = 0; bl < 2; bl++) {
        union { uint4v u; s16x8 v; } pu;
        pu.u[0] = pk[4 * bl + 0]; pu.u[1] = pk[4 * bl + 1];
        pu.u[2] = pk[4 * bl + 2]; pu.u[3] = pk[4 * bl + 3];
        const s16x8 pf = pu.v;
        const int c0 = (jt * 2 + bl) * 2 + h;  // logical V chunk
#pragma unroll
        for (int mt = 0; mt < 4; mt++) {
          const int d = mt * 32 + l31;
          s16x8 vf = *(const s16x8*)(rV + (((d << 3) + (c0 ^ (d & 7))) << 3));
          acc[mt] = MFMA32(vf, pf, acc[mt]);
        }
      }
      __builtin_amdgcn_s_setprio(0);
    }
  }

  const float l_tot = l_acc + __shfl_xor(l_acc, 32, 64);

  // ---- epilogue: transpose O via per-wave LDS slice, coalesced b128 stores
  __syncthreads();  // all waves done reading K/V tiles
  unsigned short* ep = sh + w * 4096;  // 8 KB per wave
#pragma unroll
  for (int mt = 0; mt < 4; mt++)
#pragma unroll
    for (int reg = 0; reg < 16; reg++) {
      int d = mt * 32 + (reg & 3) + 8 * (reg >> 2) + 4 * h;
      int dc = d >> 3;
      ep[(l31 << 7) + ((dc ^ (l31 & 15)) << 3) + (d & 7)] = f2bf(acc[mt][reg]);
    }
  __syncthreads();
#pragma unroll
  for (int it = 0; it < 8; it++) {
    int qr = it * 4 + (lane >> 4), cr = lane & 15;
    s16x8 v = *(const s16x8*)(ep + (qr << 7) + ((cr ^ (qr & 15)) << 3));
    *(s16x8*)(o_part + (((size_t)split * BATCH + b) * NN + i0 + w * 32 + qr) * DIM +
              cr * 8) = v;
  }
  if (lane < 32)
    l_part[((size_t)split * BATCH + b) * NN + i0 + w * 32 + lane] = l_tot;
}

// ---------------------------------------------------------------- output projection
// Fused combine + Wo GEMM + residual. Grid (64 i-tiles of 64, 8 batches), block 256.
// Wo A-frags direct from global bf16 (L1-resident); only ytile in LDS.
__global__ __launch_bounds__(256) void outp_kernel(
    const float* __restrict__ x,
    const unsigned short* __restrict__ wob,   // [128][128] bf16
    const float* __restrict__ bo,
    const unsigned short* __restrict__ o_part,
    const float* __restrict__ l_part,
    float* __restrict__ out) {
  __shared__ unsigned short ytile[64 * 136];  // 17.4 KB
  __shared__ float invl[64];
  const int b = blockIdx.y;
  const int i0 = blockIdx.x * 64;
  const int tid = threadIdx.x;

  if (tid < 64) {
    float l = 0.f;
#pragma unroll
    for (int s = 0; s < NSPLIT; s++)
      l += l_part[((size_t)s * BATCH + b) * NN + i0 + tid];
    invl[tid] = 1.0f / l;
  }
  __syncthreads();

  // Phase 1: coalesced row-major o_part reads; sum splits; normalize; LDS y-tile
#pragma unroll
  for (int k = 0; k < 4; k++) {
    int slot = k * 256 + tid;            // 1024 slots = 64 rows x 16 granules
    int i = slot >> 4, g = slot & 15;
    float o[8] = {0.f, 0.f, 0.f, 0.f, 0.f, 0.f, 0.f, 0.f};
#pragma unroll
    for (int s = 0; s < NSPLIT; s++) {
      s16x8 ov = *(const s16x8*)(o_part +
                                 (((size_t)s * BATCH + b) * NN + i0 + i) * DIM + g * 8);
#pragma unroll
      for (int jj = 0; jj < 8; jj++) o[jj] += bf2f((unsigned short)ov[jj]);
    }
    const float inv = invl[i];
    s16x8 f;
#pragma unroll
    for (int jj = 0; jj < 8; jj++) f[jj] = (short)f2bf(o[jj] * inv);
    *(s16x8*)(&ytile[i * 136 + g * 8]) = f;
  }
  __syncthreads();

  // Phase 2: Wo GEMM (A-frags from global bf16, B-frags from LDS) + bias + residual
  const int w = tid >> 6, lane = tid & 63, quad = lane >> 4, l15 = lane & 15;
  const int i = i0 + w * 16 + l15;

  s16x8 bfrag[4];
#pragma unroll
  for (int ch = 0; ch < 4; ch++)
    bfrag[ch] = *(const s16x8*)(&ytile[(w * 16 + l15) * 136 + ch * 32 + quad * 8]);

  for (int t = 0; t < 8; t++) {
    f32x4 acc = {0.f, 0.f, 0.f, 0.f};
#pragma unroll
    for (int ch = 0; ch < 4; ch++) {
      s16x8 af = *(const s16x8*)(wob + (t * 16 + l15) * DIM + ch * 32 + quad * 8);
      acc = MFMA16(af, bfrag[ch], acc);
    }
#pragma unroll
    for (int r = 0; r < 4; r++) {
      int d = t * 16 + quad * 4 + r;
      size_t idx = ((size_t)b * DIM + d) * NN + i;
      out[idx] = x[idx] + acc[r] + bo[d];
    }
  }
}

// ---------------------------------------------------------------- launch
extern "C" void kernel_launch(void* const* d_in, const int* in_sizes, int n_in,
                              void* d_out, int out_size, void* d_ws, size_t ws_size,
                              hipStream_t stream) {
  const float* x  = (const float*)d_in[0];
  const float* wq = (const float*)d_in[1];
  const float* bq = (const float*)d_in[2];
  const float* wk = (const float*)d_in[3];
  const float* bk = (const float*)d_in[4];
  const float* wv = (const float*)d_in[5];
  const float* bv = (const float*)d_in[6];
  const float* wo = (const float*)d_in[7];
  const float* bo = (const float*)d_in[8];
  float* out = (float*)d_out;

  unsigned short* ws  = (unsigned short*)d_ws;
  unsigned short* qt  = ws;                                 // 8 MB
  unsigned short* kt  = qt + (size_t)BATCH * NN * DIM;      // 8 MB
  unsigned short* vv  = kt + (size_t)BATCH * NN * DIM;      // 8 MB
  unsigned short* o_part = vv + (size_t)BATCH * NN * DIM;   // 16 MB (2 splits)
  float* l_part = (float*)(o_part + (size_t)NSPLIT * BATCH * NN * DIM);  // 256 KB
  unsigned short* wb = (unsigned short*)(l_part + (size_t)NSPLIT * BATCH * NN); // 128 KB

  hipLaunchKernelGGL(wcvt_kernel, dim3(8, 4), dim3(256), 0, stream,
                     wq, wk, wv, wo, wb);
  hipLaunchKernelGGL(qkv_kernel, dim3(64, 8), dim3(256), 0, stream,
                     x, wb, bq, bk, bv, qt, kt, vv);
  hipLaunchKernelGGL(attn_kernel, dim3(32, 8, NSPLIT), dim3(256), 0, stream,
                     qt, kt, vv, o_part, l_part);
  hipLaunchKernelGGL(outp_kernel, dim3(64, 8), dim3(256), 0, stream,
                     x, wb + 3 * WMAT, bo, o_part, l_part, out);
}

// Round 4
// 180.946 us; speedup vs baseline: 1.3120x; 1.1155x over previous
//
#include <hip/hip_runtime.h>

// Attention block: B=8, C=D=128, H=W=64, N=4096.
// out = x + Wo·(softmax(Qᵀ K /√C) @ V) + bo, Q/K/V = 1x1-conv projections.
//
// Round-15: wcvt (one-shot fp32->bf16 of all 4 weight matrices) + qkv/outp
// stage weights into padded LDS as a PURE bf16 COPY (8 s16x8 ld/st per thread
// per matrix). Round-3 lesson: per-MFMA direct-global A-frags are gathered
// multi-line L1 transactions on a dependent chain at 2 waves/SIMD — regressed
// ~30 µs. Round-1 lesson: per-block fp32->bf16 conversion (~200 VALU/thread/
// matrix x 512 blocks) is redundant work. This keeps the LDS data path of
// round-1 (bit-identical numerics) minus the conversion VALU.
// attn: byte-identical to round-12 (76.6 µs verified): 32x32x16 MFMA,
// S = K·Q -> D[j][q]; exp2(S) regs ARE the PV B-operand (V col-permuted in
// LDS); K/V double-buffered (one __syncthreads/iter); raw v_exp; setprio.
// Split-j x2: grid = 512 blocks = one co-resident cohort (2/CU).
// __launch_bounds__(256,2): acc AGPRs count against the unified file.
// Round-13 lesson: split-K rendezvous fusion = low-occupancy cold tail behind
// device fences; 4 separate launches win.

typedef float  f32x4  __attribute__((ext_vector_type(4)));
typedef float  f32x16 __attribute__((ext_vector_type(16)));
typedef short  s16x8  __attribute__((ext_vector_type(8)));
typedef short  s16x4  __attribute__((ext_vector_type(4)));
typedef unsigned uint4v __attribute__((ext_vector_type(4)));

#define MFMA16(A, Bb, Cc) __builtin_amdgcn_mfma_f32_16x16x32_bf16(A, Bb, Cc, 0, 0, 0)
#define MFMA32(A, Bb, Cc) __builtin_amdgcn_mfma_f32_32x32x16_bf16(A, Bb, Cc, 0, 0, 0)

#define BATCH 8
#define DIM   128
#define NN    4096
#define NSPLIT 2
#define JCHUNK (NN / NSPLIT)
#define NT    (JCHUNK / 64)
#define WMAT  (DIM * DIM)   // 16384 elements per weight matrix
// 1/sqrt(128) * log2(e)  (q-scale so attn can use exp2)
#define Q_SCALE 0.12751649736784776f

#if __has_builtin(__builtin_amdgcn_exp2f)
#define EXP2(x) __builtin_amdgcn_exp2f(x)
#else
#define EXP2(x) exp2f(x)
#endif

__device__ __forceinline__ unsigned short f2bf(float f) {
  union { float f; unsigned u; } v; v.f = f;
  unsigned r = v.u + 0x7FFFu + ((v.u >> 16) & 1u);  // RNE
  return (unsigned short)(r >> 16);
}
__device__ __forceinline__ float bf2f(unsigned short h) {
  union { unsigned u; float f; } v; v.u = ((unsigned)h) << 16;
  return v.f;
}
__device__ __forceinline__ s16x8 cvt8(const float* src) {
  float4 a = *(const float4*)src;
  float4 b = *(const float4*)(src + 4);
  s16x8 f;
  f[0] = (short)f2bf(a.x); f[1] = (short)f2bf(a.y);
  f[2] = (short)f2bf(a.z); f[3] = (short)f2bf(a.w);
  f[4] = (short)f2bf(b.x); f[5] = (short)f2bf(b.y);
  f[6] = (short)f2bf(b.z); f[7] = (short)f2bf(b.w);
  return f;
}

// ---------------------------------------------------------------- weight convert
// One-shot fp32->bf16 of all 4 weight matrices. Grid (8,4), 256 thr, 8 elem/thr.
__global__ __launch_bounds__(256) void wcvt_kernel(
    const float* __restrict__ wq, const float* __restrict__ wk,
    const float* __restrict__ wv, const float* __restrict__ wo,
    unsigned short* __restrict__ wb) {        // [4][128][128] bf16
  const float* src = (blockIdx.y == 0) ? wq : (blockIdx.y == 1) ? wk
                   : (blockIdx.y == 2) ? wv : wo;
  const int idx = (blockIdx.x * 256 + threadIdx.x) * 8;
  *(s16x8*)(wb + (size_t)blockIdx.y * WMAT + idx) = cvt8(src + idx);
}

// ---------------------------------------------------------------- QKV projection
// Grid (64 i-tiles, 8 batches). Block 256; each wave 16 i, 128 d, all 3 heads.
// x staged [c][i] fp32 pad 68; bf16 weights COPIED per-z into padded LDS.
__global__ __launch_bounds__(256) void qkv_kernel(
    const float* __restrict__ x,
    const unsigned short* __restrict__ wb,    // [3][128][128] bf16 (q,k,v)
    const float* __restrict__ bq, const float* __restrict__ bk,
    const float* __restrict__ bv,
    unsigned short* __restrict__ qt,          // [B][N][D]
    unsigned short* __restrict__ kt,          // [B][N][D]
    unsigned short* __restrict__ vv) {        // [B][D][N]
  __shared__ float xs[DIM * 68];              // 34.8 KB
  __shared__ unsigned short wls[DIM * 136];   // 34.8 KB (one z at a time)
  const int b = blockIdx.y;
  const int i0 = blockIdx.x * 64;
  const int tid = threadIdx.x;

  for (int idx = tid; idx < 2048; idx += 256) {
    int c = idx >> 4, i4 = idx & 15;
    float4 val = *(const float4*)(x + ((size_t)(b * DIM + c)) * NN + i0 + i4 * 4);
    xs[c * 68 + i4 * 4 + 0] = val.x;
    xs[c * 68 + i4 * 4 + 1] = val.y;
    xs[c * 68 + i4 * 4 + 2] = val.z;
    xs[c * 68 + i4 * 4 + 3] = val.w;
  }
  __syncthreads();

  const int w = tid >> 6, lane = tid & 63, quad = lane >> 4, l15 = lane & 15;
  const int iloc = w * 16 + l15;

  // B-frags from x tile (once, reused by all 3 heads)
  s16x8 bfrag[4];
#pragma unroll
  for (int ch = 0; ch < 4; ch++) {
    s16x8 f;
#pragma unroll
    for (int jj = 0; jj < 8; jj++) {
      int c = ch * 32 + quad * 8 + jj;
      f[jj] = (short)f2bf(xs[c * 68 + iloc]);
    }
    bfrag[ch] = f;
  }

  const int i = i0 + iloc;
  const int wr = tid >> 4, wc = tid & 15;   // weight staging coords

  for (int z = 0; z < 3; z++) {
    __syncthreads();  // prior z's wls reads done
    const unsigned short* wz = wb + (size_t)z * WMAT;
#pragma unroll
    for (int it = 0; it < 8; it++) {
      const int row = it * 16 + wr;
      *(s16x8*)(&wls[row * 136 + wc * 8]) = *(const s16x8*)(wz + row * DIM + wc * 8);
    }
    __syncthreads();

    const float* bias = (z == 0) ? bq : (z == 1) ? bk : bv;
    const float sc = (z == 0) ? Q_SCALE : 1.0f;

    for (int t = 0; t < 8; t++) {
      const int dl = t * 16;
      f32x4 acc = {0.f, 0.f, 0.f, 0.f};
#pragma unroll
      for (int ch = 0; ch < 4; ch++) {
        s16x8 af = *(const s16x8*)(&wls[(dl + l15) * 136 + ch * 32 + quad * 8]);
        acc = MFMA16(af, bfrag[ch], acc);
      }
      if (z < 2) {
        unsigned short* dstb = (z == 0) ? qt : kt;
        s16x4 o;
#pragma unroll
        for (int r = 0; r < 4; r++) {
          int d = dl + quad * 4 + r;
          o[r] = (short)f2bf((acc[r] + bias[d]) * sc);
        }
        *(s16x4*)(dstb + ((size_t)b * NN + i) * DIM + dl + quad * 4) = o;
      } else {
#pragma unroll
        for (int r = 0; r < 4; r++) {
          int d = dl + quad * 4 + r;
          vv[((size_t)b * DIM + d) * NN + i] = f2bf(acc[r] + bias[d]);
        }
      }
    }
  }
}

// ---------------------------------------------------------------- flash attention
// Grid (32 q-tiles of 128, 8 batches, 2 j-splits) = 512 blocks. 4 waves x 32 q.
__global__ __launch_bounds__(256, 2) void attn_kernel(
    const unsigned short* __restrict__ qt,
    const unsigned short* __restrict__ kt,
    const unsigned short* __restrict__ vv,
    unsigned short* __restrict__ o_part,   // [S][B][N][D] bf16, un-normalized
    float* __restrict__ l_part) {          // [S][B][N]
  __shared__ unsigned short sh[32768];     // 64 KB: 2 x (K 16 KB + V 16 KB)
  const int b = blockIdx.y;
  const int i0 = blockIdx.x * 128;
  const int split = blockIdx.z;
  const int jbase = split * JCHUNK;
  const int tid = threadIdx.x;
  const int w = tid >> 6, lane = tid & 63;
  const int l31 = lane & 31, h = lane >> 5;

  const unsigned short* kb = kt + (size_t)b * NN * DIM;
  const unsigned short* vb = vv + (size_t)b * DIM * NN;

  // persistent Q B-frags: B[k=d][n=q], lane n=l31, k = 16*kc + 8*h + i
  s16x8 qfrag[8];
  {
    const unsigned short* qrow =
        qt + ((size_t)b * NN + i0 + w * 32 + l31) * DIM + h * 8;
#pragma unroll
    for (int kc = 0; kc < 8; kc++)
      qfrag[kc] = *(const s16x8*)(qrow + kc * 16);
  }

  f32x16 acc[4];
#pragma unroll
  for (int mt = 0; mt < 4; mt++)
#pragma unroll
    for (int e = 0; e < 16; e++) acc[mt][e] = 0.f;
  float l_acc = 0.f;

  // staging thread coordinates (iter-invariant)
  const int kr = tid >> 4, kc_ = tid & 15;   // K: row kr + it*16, chunk kc_
  const int vr = tid >> 3, vc = tid & 7;     // V: row vr + it*32, 8-col group vc
  const int vch0 = (vc & 1) ? (vc - 1) : vc; // V column permutation
  const int vch1 = (vc & 1) ? vc : (vc + 1);
  const int vpos = (vc & 1) * 4;

  s16x8 kpre[4], vpre[4];

  // ---- prologue: tile 0 -> regs -> buf0; tile 1 -> regs
#pragma unroll
  for (int it = 0; it < 4; it++) {
    kpre[it] = *(const s16x8*)(kb + (size_t)(jbase + it * 16 + kr) * DIM + kc_ * 8);
    vpre[it] = *(const s16x8*)(vb + (size_t)(it * 32 + vr) * NN + jbase + vc * 8);
  }
#pragma unroll
  for (int it = 0; it < 4; it++) {
    const int r = it * 16 + kr;
    *(s16x8*)(sh + (((r << 4) + (kc_ ^ (r & 15))) << 3)) = kpre[it];
    const int r2 = it * 32 + vr;
    union { s16x8 v8; s16x4 v4[2]; } sp; sp.v8 = vpre[it];
    *(s16x4*)(sh + 8192 + (((r2 << 3) + (vch0 ^ (r2 & 7))) << 3) + vpos) = sp.v4[0];
    *(s16x4*)(sh + 8192 + (((r2 << 3) + (vch1 ^ (r2 & 7))) << 3) + vpos) = sp.v4[1];
  }
#pragma unroll
  for (int it = 0; it < 4; it++) {
    kpre[it] = *(const s16x8*)(kb + (size_t)(jbase + 64 + it * 16 + kr) * DIM + kc_ * 8);
    vpre[it] = *(const s16x8*)(vb + (size_t)(it * 32 + vr) * NN + jbase + 64 + vc * 8);
  }

  for (int t = 0; t < NT; t++) {
    // single barrier per iter: buf[t&1] (written last iter) is ready, and all
    // waves' reads of buf[(t+1)&1] (= last iter's compute buffer) are done.
    __syncthreads();

    // ---- write prefetched tile t+1 -> other buffer (swizzled; V col-permuted)
    if (t + 1 < NT) {
      unsigned short* wb2 = sh + ((~t & 1) << 14);
#pragma unroll
      for (int it = 0; it < 4; it++) {
        const int r = it * 16 + kr;
        *(s16x8*)(wb2 + (((r << 4) + (kc_ ^ (r & 15))) << 3)) = kpre[it];
        const int r2 = it * 32 + vr;
        union { s16x8 v8; s16x4 v4[2]; } sp; sp.v8 = vpre[it];
        *(s16x4*)(wb2 + 8192 + (((r2 << 3) + (vch0 ^ (r2 & 7))) << 3) + vpos) = sp.v4[0];
        *(s16x4*)(wb2 + 8192 + (((r2 << 3) + (vch1 ^ (r2 & 7))) << 3) + vpos) = sp.v4[1];
      }
    }

    // ---- prefetch tile t+2 into registers (no barrier dependency)
    if (t + 2 < NT) {
      const int jn = jbase + (t + 2) * 64;
#pragma unroll
      for (int it = 0; it < 4; it++) {
        kpre[it] = *(const s16x8*)(kb + (size_t)(jn + it * 16 + kr) * DIM + kc_ * 8);
        vpre[it] = *(const s16x8*)(vb + (size_t)(it * 32 + vr) * NN + jn + vc * 8);
      }
    }

    const unsigned short* rK = sh + ((t & 1) << 14);
    const unsigned short* rV = rK + 8192;

    // ---- S = K·Q -> D[j][q]; P = exp2(S); PV straight from S registers
#pragma unroll
    for (int jt = 0; jt < 2; jt++) {
      f32x16 S;
#pragma unroll
      for (int e = 0; e < 16; e++) S[e] = 0.f;
      const int j = jt * 32 + l31;
      __builtin_amdgcn_s_setprio(1);
#pragma unroll
      for (int kc = 0; kc < 8; kc++) {
        s16x8 kf = *(const s16x8*)(rK + (((j << 4) + ((2 * kc + h) ^ (j & 15))) << 3));
        S = MFMA32(kf, qfrag[kc], S);
      }
      __builtin_amdgcn_s_setprio(0);
      unsigned pk[8];
#pragma unroll
      for (int p = 0; p < 8; p++) {
        float e0 = EXP2(S[2 * p]), e1 = EXP2(S[2 * p + 1]);
        l_acc += e0 + e1;
        union { float f; unsigned u; } u0, u1; u0.f = e0; u1.f = e1;
        pk[p] = __builtin_amdgcn_perm(u1.u, u0.u, 0x07060302u);  // [bf16(e0),bf16(e1)]
      }
      __builtin_amdgcn_s_setprio(1);
#pragma unroll
      for (int bl = 0; bl < 2; bl++) {
        union { uint4v u; s16x8 v; } pu;
        pu.u[0] = pk[4 * bl + 0]; pu.u[1] = pk[4 * bl + 1];
        pu.u[2] = pk[4 * bl + 2]; pu.u[3] = pk[4 * bl + 3];
        const s16x8 pf = pu.v;
        const int c0 = (jt * 2 + bl) * 2 + h;  // logical V chunk
#pragma unroll
        for (int mt = 0; mt < 4; mt++) {
          const int d = mt * 32 + l31;
          s16x8 vf = *(const s16x8*)(rV + (((d << 3) + (c0 ^ (d & 7))) << 3));
          acc[mt] = MFMA32(vf, pf, acc[mt]);
        }
      }
      __builtin_amdgcn_s_setprio(0);
    }
  }

  const float l_tot = l_acc + __shfl_xor(l_acc, 32, 64);

  // ---- epilogue: transpose O via per-wave LDS slice, coalesced b128 stores
  __syncthreads();  // all waves done reading K/V tiles
  unsigned short* ep = sh + w * 4096;  // 8 KB per wave
#pragma unroll
  for (int mt = 0; mt < 4; mt++)
#pragma unroll
    for (int reg = 0; reg < 16; reg++) {
      int d = mt * 32 + (reg & 3) + 8 * (reg >> 2) + 4 * h;
      int dc = d >> 3;
      ep[(l31 << 7) + ((dc ^ (l31 & 15)) << 3) + (d & 7)] = f2bf(acc[mt][reg]);
    }
  __syncthreads();
#pragma unroll
  for (int it = 0; it < 8; it++) {
    int qr = it * 4 + (lane >> 4), cr = lane & 15;
    s16x8 v = *(const s16x8*)(ep + (qr << 7) + ((cr ^ (qr & 15)) << 3));
    *(s16x8*)(o_part + (((size_t)split * BATCH + b) * NN + i0 + w * 32 + qr) * DIM +
              cr * 8) = v;
  }
  if (lane < 32)
    l_part[((size_t)split * BATCH + b) * NN + i0 + w * 32 + lane] = l_tot;
}

// ---------------------------------------------------------------- output projection
// Fused combine + Wo GEMM + residual. Grid (64 i-tiles of 64, 8 batches), block 256.
// Wo bf16 COPIED into padded LDS (A-frags via ds_read_b128).
__global__ __launch_bounds__(256) void outp_kernel(
    const float* __restrict__ x,
    const unsigned short* __restrict__ wob,   // [128][128] bf16
    const float* __restrict__ bo,
    const unsigned short* __restrict__ o_part,
    const float* __restrict__ l_part,
    float* __restrict__ out) {
  __shared__ unsigned short ytile[64 * 136];  // 17.4 KB
  __shared__ unsigned short wls[DIM * 136];   // 34.8 KB
  __shared__ float invl[64];
  const int b = blockIdx.y;
  const int i0 = blockIdx.x * 64;
  const int tid = threadIdx.x;
  const int wr = tid >> 4, wc = tid & 15;

  // stage Wo (bf16 copy, padded LDS)
#pragma unroll
  for (int it = 0; it < 8; it++) {
    const int row = it * 16 + wr;
    *(s16x8*)(&wls[row * 136 + wc * 8]) = *(const s16x8*)(wob + row * DIM + wc * 8);
  }

  if (tid < 64) {
    float l = 0.f;
#pragma unroll
    for (int s = 0; s < NSPLIT; s++)
      l += l_part[((size_t)s * BATCH + b) * NN + i0 + tid];
    invl[tid] = 1.0f / l;
  }
  __syncthreads();

  // Phase 1: coalesced row-major o_part reads; sum splits; normalize; LDS y-tile
#pragma unroll
  for (int k = 0; k < 4; k++) {
    int slot = k * 256 + tid;            // 1024 slots = 64 rows x 16 granules
    int i = slot >> 4, g = slot & 15;
    float o[8] = {0.f, 0.f, 0.f, 0.f, 0.f, 0.f, 0.f, 0.f};
#pragma unroll
    for (int s = 0; s < NSPLIT; s++) {
      s16x8 ov = *(const s16x8*)(o_part +
                                 (((size_t)s * BATCH + b) * NN + i0 + i) * DIM + g * 8);
#pragma unroll
      for (int jj = 0; jj < 8; jj++) o[jj] += bf2f((unsigned short)ov[jj]);
    }
    const float inv = invl[i];
    s16x8 f;
#pragma unroll
    for (int jj = 0; jj < 8; jj++) f[jj] = (short)f2bf(o[jj] * inv);
    *(s16x8*)(&ytile[i * 136 + g * 8]) = f;
  }
  __syncthreads();

  // Phase 2: Wo GEMM from LDS A- and B-frags + bias + residual
  const int w = tid >> 6, lane = tid & 63, quad = lane >> 4, l15 = lane & 15;
  const int i = i0 + w * 16 + l15;

  s16x8 bfrag[4];
#pragma unroll
  for (int ch = 0; ch < 4; ch++)
    bfrag[ch] = *(const s16x8*)(&ytile[(w * 16 + l15) * 136 + ch * 32 + quad * 8]);

  for (int t = 0; t < 8; t++) {
    f32x4 acc = {0.f, 0.f, 0.f, 0.f};
#pragma unroll
    for (int ch = 0; ch < 4; ch++) {
      s16x8 af = *(const s16x8*)(&wls[(t * 16 + l15) * 136 + ch * 32 + quad * 8]);
      acc = MFMA16(af, bfrag[ch], acc);
    }
#pragma unroll
    for (int r = 0; r < 4; r++) {
      int d = t * 16 + quad * 4 + r;
      size_t idx = ((size_t)b * DIM + d) * NN + i;
      out[idx] = x[idx] + acc[r] + bo[d];
    }
  }
}

// ---------------------------------------------------------------- launch
extern "C" void kernel_launch(void* const* d_in, const int* in_sizes, int n_in,
                              void* d_out, int out_size, void* d_ws, size_t ws_size,
                              hipStream_t stream) {
  const float* x  = (const float*)d_in[0];
  const float* wq = (const float*)d_in[1];
  const float* bq = (const float*)d_in[2];
  const float* wk = (const float*)d_in[3];
  const float* bk = (const float*)d_in[4];
  const float* wv = (const float*)d_in[5];
  const float* bv = (const float*)d_in[6];
  const float* wo = (const float*)d_in[7];
  const float* bo = (const float*)d_in[8];
  float* out = (float*)d_out;

  unsigned short* ws  = (unsigned short*)d_ws;
  unsigned short* qt  = ws;                                 // 8 MB
  unsigned short* kt  = qt + (size_t)BATCH * NN * DIM;      // 8 MB
  unsigned short* vv  = kt + (size_t)BATCH * NN * DIM;      // 8 MB
  unsigned short* o_part = vv + (size_t)BATCH * NN * DIM;   // 16 MB (2 splits)
  float* l_part = (float*)(o_part + (size_t)NSPLIT * BATCH * NN * DIM);  // 256 KB
  unsigned short* wb = (unsigned short*)(l_part + (size_t)NSPLIT * BATCH * NN); // 128 KB

  hipLaunchKernelGGL(wcvt_kernel, dim3(8, 4), dim3(256), 0, stream,
                     wq, wk, wv, wo, wb);
  hipLaunchKernelGGL(qkv_kernel, dim3(64, 8), dim3(256), 0, stream,
                     x, wb, bq, bk, bv, qt, kt, vv);
  hipLaunchKernelGGL(attn_kernel, dim3(32, 8, NSPLIT), dim3(256), 0, stream,
                     qt, kt, vv, o_part, l_part);
  hipLaunchKernelGGL(outp_kernel, dim3(64, 8), dim3(256), 0, stream,
                     x, wb + 3 * WMAT, bo, o_part, l_part, out);
}

// Round 5
// 178.949 us; speedup vs baseline: 1.3267x; 1.0112x over previous
//
#include <hip/hip_runtime.h>

// Attention block: B=8, C=D=128, H=W=64, N=4096.
// out = x + Wo·(softmax(Qᵀ K /√C) @ V) + bo, Q/K/V = 1x1-conv projections.
//
// Round-16: non-attn cost is LATENCY/serialization, not instruction count
// (R1 convert-in-block == R4 copy-in-block+wcvt == ~95-100 µs non-attn, vs
// ~20 µs roofline). Restructure:
//   qkv z-split: grid (64,8,3) — one head per block. LDS = x-tile bf16
//   [128][72] (18.4 KB) + one weight [128][136] (34.8 KB) = 53.2 KB ->
//   3 blocks/CU, ONE barrier/block (was 6, 2 blocks/CU). Weight converted
//   fp32->bf16 in-block (R1/R4 A/B: conversion == copy, so wcvt kernel
//   deleted -> 3 launches). x read 3x but z-siblings are 512 block-ids apart
//   (same XCD mod 8) -> L2-hot. Bit-identical numerics.
//   outp: o_part loads (8 x s16x8) issued into registers BEFORE Wo staging +
//   barrier -> L2 latency hidden under staging. Same sum order, bit-identical.
// attn: byte-identical to round-12 (76.6 µs verified): 32x32x16 MFMA,
// S = K·Q -> D[j][q]; exp2(S) regs ARE the PV B-operand (V col-permuted in
// LDS); K/V double-buffered (one __syncthreads/iter); raw v_exp; setprio.
// Split-j x2: grid = 512 blocks = one co-resident cohort (2/CU).
// __launch_bounds__(256,2): acc AGPRs count against the unified file.
// R13 lesson: split-K rendezvous fusion = low-occupancy cold tail. R3 lesson:
// per-MFMA direct-global weight frags = gathered L1 transactions, regressed.

typedef float  f32x4  __attribute__((ext_vector_type(4)));
typedef float  f32x16 __attribute__((ext_vector_type(16)));
typedef short  s16x8  __attribute__((ext_vector_type(8)));
typedef short  s16x4  __attribute__((ext_vector_type(4)));
typedef unsigned uint4v __attribute__((ext_vector_type(4)));

#define MFMA16(A, Bb, Cc) __builtin_amdgcn_mfma_f32_16x16x32_bf16(A, Bb, Cc, 0, 0, 0)
#define MFMA32(A, Bb, Cc) __builtin_amdgcn_mfma_f32_32x32x16_bf16(A, Bb, Cc, 0, 0, 0)

#define BATCH 8
#define DIM   128
#define NN    4096
#define NSPLIT 2
#define JCHUNK (NN / NSPLIT)
#define NT    (JCHUNK / 64)
// 1/sqrt(128) * log2(e)  (q-scale so attn can use exp2)
#define Q_SCALE 0.12751649736784776f

#if __has_builtin(__builtin_amdgcn_exp2f)
#define EXP2(x) __builtin_amdgcn_exp2f(x)
#else
#define EXP2(x) exp2f(x)
#endif

__device__ __forceinline__ unsigned short f2bf(float f) {
  union { float f; unsigned u; } v; v.f = f;
  unsigned r = v.u + 0x7FFFu + ((v.u >> 16) & 1u);  // RNE
  return (unsigned short)(r >> 16);
}
__device__ __forceinline__ float bf2f(unsigned short h) {
  union { unsigned u; float f; } v; v.u = ((unsigned)h) << 16;
  return v.f;
}
__device__ __forceinline__ s16x8 cvt8(const float* src) {
  float4 a = *(const float4*)src;
  float4 b = *(const float4*)(src + 4);
  s16x8 f;
  f[0] = (short)f2bf(a.x); f[1] = (short)f2bf(a.y);
  f[2] = (short)f2bf(a.z); f[3] = (short)f2bf(a.w);
  f[4] = (short)f2bf(b.x); f[5] = (short)f2bf(b.y);
  f[6] = (short)f2bf(b.z); f[7] = (short)f2bf(b.w);
  return f;
}

// ---------------------------------------------------------------- QKV projection
// Grid (64 i-tiles, 8 batches, 3 heads). Block 256; each wave 16 i, 128 d.
// x staged [c][i] bf16 stride 72; one weight matrix converted into padded LDS.
// Both stagings independent -> single barrier.
__global__ __launch_bounds__(256, 3) void qkv_kernel(
    const float* __restrict__ x,
    const float* __restrict__ wq, const float* __restrict__ wk,
    const float* __restrict__ wv,
    const float* __restrict__ bq, const float* __restrict__ bk,
    const float* __restrict__ bv,
    unsigned short* __restrict__ qt,          // [B][N][D]
    unsigned short* __restrict__ kt,          // [B][N][D]
    unsigned short* __restrict__ vv) {        // [B][D][N]
  __shared__ unsigned short xs16[DIM * 72];   // 18.4 KB (stride 72: 16B-aligned rows)
  __shared__ unsigned short wls[DIM * 136];   // 34.8 KB
  const int b = blockIdx.y;
  const int i0 = blockIdx.x * 64;
  const int z = blockIdx.z;
  const int tid = threadIdx.x;

  const float* wsrc = (z == 0) ? wq : (z == 1) ? wk : wv;
  const float* bias = (z == 0) ? bq : (z == 1) ? bk : bv;
  const float sc = (z == 0) ? Q_SCALE : 1.0f;

  // stage weight z (fp32 -> bf16, padded LDS)
  const int wr = tid >> 4, wc = tid & 15;
#pragma unroll
  for (int it = 0; it < 8; it++) {
    const int row = it * 16 + wr;
    *(s16x8*)(&wls[row * 136 + wc * 8]) = cvt8(wsrc + row * DIM + wc * 8);
  }
  // stage x tile [c][i] as bf16 (8 floats -> s16x8 per slot)
  for (int idx = tid; idx < 1024; idx += 256) {
    int c = idx >> 3, i8 = idx & 7;
    *(s16x8*)(&xs16[c * 72 + i8 * 8]) =
        cvt8(x + ((size_t)(b * DIM + c)) * NN + i0 + i8 * 8);
  }
  __syncthreads();

  const int w = tid >> 6, lane = tid & 63, quad = lane >> 4, l15 = lane & 15;
  const int iloc = w * 16 + l15;
  const int i = i0 + iloc;

  // B-frags from x tile
  s16x8 bfrag[4];
#pragma unroll
  for (int ch = 0; ch < 4; ch++) {
    s16x8 f;
#pragma unroll
    for (int jj = 0; jj < 8; jj++) {
      int c = ch * 32 + quad * 8 + jj;
      f[jj] = (short)xs16[c * 72 + iloc];
    }
    bfrag[ch] = f;
  }

  for (int t = 0; t < 8; t++) {
    const int dl = t * 16;
    f32x4 acc = {0.f, 0.f, 0.f, 0.f};
#pragma unroll
    for (int ch = 0; ch < 4; ch++) {
      s16x8 af = *(const s16x8*)(&wls[(dl + l15) * 136 + ch * 32 + quad * 8]);
      acc = MFMA16(af, bfrag[ch], acc);
    }
    if (z < 2) {
      unsigned short* dstb = (z == 0) ? qt : kt;
      s16x4 o;
#pragma unroll
      for (int r = 0; r < 4; r++) {
        int d = dl + quad * 4 + r;
        o[r] = (short)f2bf((acc[r] + bias[d]) * sc);
      }
      *(s16x4*)(dstb + ((size_t)b * NN + i) * DIM + dl + quad * 4) = o;
    } else {
#pragma unroll
      for (int r = 0; r < 4; r++) {
        int d = dl + quad * 4 + r;
        vv[((size_t)b * DIM + d) * NN + i] = f2bf(acc[r] + bias[d]);
      }
    }
  }
}

// ---------------------------------------------------------------- flash attention
// Grid (32 q-tiles of 128, 8 batches, 2 j-splits) = 512 blocks. 4 waves x 32 q.
__global__ __launch_bounds__(256, 2) void attn_kernel(
    const unsigned short* __restrict__ qt,
    const unsigned short* __restrict__ kt,
    const unsigned short* __restrict__ vv,
    unsigned short* __restrict__ o_part,   // [S][B][N][D] bf16, un-normalized
    float* __restrict__ l_part) {          // [S][B][N]
  __shared__ unsigned short sh[32768];     // 64 KB: 2 x (K 16 KB + V 16 KB)
  const int b = blockIdx.y;
  const int i0 = blockIdx.x * 128;
  const int split = blockIdx.z;
  const int jbase = split * JCHUNK;
  const int tid = threadIdx.x;
  const int w = tid >> 6, lane = tid & 63;
  const int l31 = lane & 31, h = lane >> 5;

  const unsigned short* kb = kt + (size_t)b * NN * DIM;
  const unsigned short* vb = vv + (size_t)b * DIM * NN;

  // persistent Q B-frags: B[k=d][n=q], lane n=l31, k = 16*kc + 8*h + i
  s16x8 qfrag[8];
  {
    const unsigned short* qrow =
        qt + ((size_t)b * NN + i0 + w * 32 + l31) * DIM + h * 8;
#pragma unroll
    for (int kc = 0; kc < 8; kc++)
      qfrag[kc] = *(const s16x8*)(qrow + kc * 16);
  }

  f32x16 acc[4];
#pragma unroll
  for (int mt = 0; mt < 4; mt++)
#pragma unroll
    for (int e = 0; e < 16; e++) acc[mt][e] = 0.f;
  float l_acc = 0.f;

  // staging thread coordinates (iter-invariant)
  const int kr = tid >> 4, kc_ = tid & 15;   // K: row kr + it*16, chunk kc_
  const int vr = tid >> 3, vc = tid & 7;     // V: row vr + it*32, 8-col group vc
  const int vch0 = (vc & 1) ? (vc - 1) : vc; // V column permutation
  const int vch1 = (vc & 1) ? vc : (vc + 1);
  const int vpos = (vc & 1) * 4;

  s16x8 kpre[4], vpre[4];

  // ---- prologue: tile 0 -> regs -> buf0; tile 1 -> regs
#pragma unroll
  for (int it = 0; it < 4; it++) {
    kpre[it] = *(const s16x8*)(kb + (size_t)(jbase + it * 16 + kr) * DIM + kc_ * 8);
    vpre[it] = *(const s16x8*)(vb + (size_t)(it * 32 + vr) * NN + jbase + vc * 8);
  }
#pragma unroll
  for (int it = 0; it < 4; it++) {
    const int r = it * 16 + kr;
    *(s16x8*)(sh + (((r << 4) + (kc_ ^ (r & 15))) << 3)) = kpre[it];
    const int r2 = it * 32 + vr;
    union { s16x8 v8; s16x4 v4[2]; } sp; sp.v8 = vpre[it];
    *(s16x4*)(sh + 8192 + (((r2 << 3) + (vch0 ^ (r2 & 7))) << 3) + vpos) = sp.v4[0];
    *(s16x4*)(sh + 8192 + (((r2 << 3) + (vch1 ^ (r2 & 7))) << 3) + vpos) = sp.v4[1];
  }
#pragma unroll
  for (int it = 0; it < 4; it++) {
    kpre[it] = *(const s16x8*)(kb + (size_t)(jbase + 64 + it * 16 + kr) * DIM + kc_ * 8);
    vpre[it] = *(const s16x8*)(vb + (size_t)(it * 32 + vr) * NN + jbase + 64 + vc * 8);
  }

  for (int t = 0; t < NT; t++) {
    // single barrier per iter: buf[t&1] (written last iter) is ready, and all
    // waves' reads of buf[(t+1)&1] (= last iter's compute buffer) are done.
    __syncthreads();

    // ---- write prefetched tile t+1 -> other buffer (swizzled; V col-permuted)
    if (t + 1 < NT) {
      unsigned short* wb2 = sh + ((~t & 1) << 14);
#pragma unroll
      for (int it = 0; it < 4; it++) {
        const int r = it * 16 + kr;
        *(s16x8*)(wb2 + (((r << 4) + (kc_ ^ (r & 15))) << 3)) = kpre[it];
        const int r2 = it * 32 + vr;
        union { s16x8 v8; s16x4 v4[2]; } sp; sp.v8 = vpre[it];
        *(s16x4*)(wb2 + 8192 + (((r2 << 3) + (vch0 ^ (r2 & 7))) << 3) + vpos) = sp.v4[0];
        *(s16x4*)(wb2 + 8192 + (((r2 << 3) + (vch1 ^ (r2 & 7))) << 3) + vpos) = sp.v4[1];
      }
    }

    // ---- prefetch tile t+2 into registers (no barrier dependency)
    if (t + 2 < NT) {
      const int jn = jbase + (t + 2) * 64;
#pragma unroll
      for (int it = 0; it < 4; it++) {
        kpre[it] = *(const s16x8*)(kb + (size_t)(jn + it * 16 + kr) * DIM + kc_ * 8);
        vpre[it] = *(const s16x8*)(vb + (size_t)(it * 32 + vr) * NN + jn + vc * 8);
      }
    }

    const unsigned short* rK = sh + ((t & 1) << 14);
    const unsigned short* rV = rK + 8192;

    // ---- S = K·Q -> D[j][q]; P = exp2(S); PV straight from S registers
#pragma unroll
    for (int jt = 0; jt < 2; jt++) {
      f32x16 S;
#pragma unroll
      for (int e = 0; e < 16; e++) S[e] = 0.f;
      const int j = jt * 32 + l31;
      __builtin_amdgcn_s_setprio(1);
#pragma unroll
      for (int kc = 0; kc < 8; kc++) {
        s16x8 kf = *(const s16x8*)(rK + (((j << 4) + ((2 * kc + h) ^ (j & 15))) << 3));
        S = MFMA32(kf, qfrag[kc], S);
      }
      __builtin_amdgcn_s_setprio(0);
      unsigned pk[8];
#pragma unroll
      for (int p = 0; p < 8; p++) {
        float e0 = EXP2(S[2 * p]), e1 = EXP2(S[2 * p + 1]);
        l_acc += e0 + e1;
        union { float f; unsigned u; } u0, u1; u0.f = e0; u1.f = e1;
        pk[p] = __builtin_amdgcn_perm(u1.u, u0.u, 0x07060302u);  // [bf16(e0),bf16(e1)]
      }
      __builtin_amdgcn_s_setprio(1);
#pragma unroll
      for (int bl = 0; bl < 2; bl++) {
        union { uint4v u; s16x8 v; } pu;
        pu.u[0] = pk[4 * bl + 0]; pu.u[1] = pk[4 * bl + 1];
        pu.u[2] = pk[4 * bl + 2]; pu.u[3] = pk[4 * bl + 3];
        const s16x8 pf = pu.v;
        const int c0 = (jt * 2 + bl) * 2 + h;  // logical V chunk
#pragma unroll
        for (int mt = 0; mt < 4; mt++) {
          const int d = mt * 32 + l31;
          s16x8 vf = *(const s16x8*)(rV + (((d << 3) + (c0 ^ (d & 7))) << 3));
          acc[mt] = MFMA32(vf, pf, acc[mt]);
        }
      }
      __builtin_amdgcn_s_setprio(0);
    }
  }

  const float l_tot = l_acc + __shfl_xor(l_acc, 32, 64);

  // ---- epilogue: transpose O via per-wave LDS slice, coalesced b128 stores
  __syncthreads();  // all waves done reading K/V tiles
  unsigned short* ep = sh + w * 4096;  // 8 KB per wave
#pragma unroll
  for (int mt = 0; mt < 4; mt++)
#pragma unroll
    for (int reg = 0; reg < 16; reg++) {
      int d = mt * 32 + (reg & 3) + 8 * (reg >> 2) + 4 * h;
      int dc = d >> 3;
      ep[(l31 << 7) + ((dc ^ (l31 & 15)) << 3) + (d & 7)] = f2bf(acc[mt][reg]);
    }
  __syncthreads();
#pragma unroll
  for (int it = 0; it < 8; it++) {
    int qr = it * 4 + (lane >> 4), cr = lane & 15;
    s16x8 v = *(const s16x8*)(ep + (qr << 7) + ((cr ^ (qr & 15)) << 3));
    *(s16x8*)(o_part + (((size_t)split * BATCH + b) * NN + i0 + w * 32 + qr) * DIM +
              cr * 8) = v;
  }
  if (lane < 32)
    l_part[((size_t)split * BATCH + b) * NN + i0 + w * 32 + lane] = l_tot;
}

// ---------------------------------------------------------------- output projection
// Fused combine + Wo GEMM + residual. Grid (64 i-tiles of 64, 8 batches), block 256.
// o_part loads issued into registers BEFORE Wo staging (latency hidden).
__global__ __launch_bounds__(256, 3) void outp_kernel(
    const float* __restrict__ x,
    const float* __restrict__ wo,
    const float* __restrict__ bo,
    const unsigned short* __restrict__ o_part,
    const float* __restrict__ l_part,
    float* __restrict__ out) {
  __shared__ unsigned short ytile[64 * 136];  // 17.4 KB
  __shared__ unsigned short wls[DIM * 136];   // 34.8 KB
  __shared__ float invl[64];
  const int b = blockIdx.y;
  const int i0 = blockIdx.x * 64;
  const int tid = threadIdx.x;
  const int ir = tid >> 4, g = tid & 15;

  // issue all 8 o_part granule loads early (L2 latency hides under Wo staging)
  s16x8 ov[4][2];
#pragma unroll
  for (int k = 0; k < 4; k++)
#pragma unroll
    for (int s = 0; s < NSPLIT; s++)
      ov[k][s] = *(const s16x8*)(o_part +
          (((size_t)s * BATCH + b) * NN + i0 + k * 16 + ir) * DIM + g * 8);

  // stage Wo (fp32 -> bf16, padded LDS)
  const int wr = tid >> 4, wc = tid & 15;
#pragma unroll
  for (int it = 0; it < 8; it++) {
    const int row = it * 16 + wr;
    *(s16x8*)(&wls[row * 136 + wc * 8]) = cvt8(wo + row * DIM + wc * 8);
  }

  if (tid < 64) {
    float l = 0.f;
#pragma unroll
    for (int s = 0; s < NSPLIT; s++)
      l += l_part[((size_t)s * BATCH + b) * NN + i0 + tid];
    invl[tid] = 1.0f / l;
  }
  __syncthreads();

  // Phase 1: combine splits from registers; normalize; LDS y-tile
#pragma unroll
  for (int k = 0; k < 4; k++) {
    const int i = k * 16 + ir;
    const float inv = invl[i];
    s16x8 f;
#pragma unroll
    for (int jj = 0; jj < 8; jj++) {
      float o = bf2f((unsigned short)ov[k][0][jj]) + bf2f((unsigned short)ov[k][1][jj]);
      f[jj] = (short)f2bf(o * inv);
    }
    *(s16x8*)(&ytile[i * 136 + g * 8]) = f;
  }
  __syncthreads();

  // Phase 2: Wo GEMM from LDS A- and B-frags + bias + residual
  const int w = tid >> 6, lane = tid & 63, quad = lane >> 4, l15 = lane & 15;
  const int i = i0 + w * 16 + l15;

  s16x8 bfrag[4];
#pragma unroll
  for (int ch = 0; ch < 4; ch++)
    bfrag[ch] = *(const s16x8*)(&ytile[(w * 16 + l15) * 136 + ch * 32 + quad * 8]);

  for (int t = 0; t < 8; t++) {
    f32x4 acc = {0.f, 0.f, 0.f, 0.f};
#pragma unroll
    for (int ch = 0; ch < 4; ch++) {
      s16x8 af = *(const s16x8*)(&wls[(t * 16 + l15) * 136 + ch * 32 + quad * 8]);
      acc = MFMA16(af, bfrag[ch], acc);
    }
#pragma unroll
    for (int r = 0; r < 4; r++) {
      int d = t * 16 + quad * 4 + r;
      size_t idx = ((size_t)b * DIM + d) * NN + i;
      out[idx] = x[idx] + acc[r] + bo[d];
    }
  }
}

// ---------------------------------------------------------------- launch
extern "C" void kernel_launch(void* const* d_in, const int* in_sizes, int n_in,
                              void* d_out, int out_size, void* d_ws, size_t ws_size,
                              hipStream_t stream) {
  const float* x  = (const float*)d_in[0];
  const float* wq = (const float*)d_in[1];
  const float* bq = (const float*)d_in[2];
  const float* wk = (const float*)d_in[3];
  const float* bk = (const float*)d_in[4];
  const float* wv = (const float*)d_in[5];
  const float* bv = (const float*)d_in[6];
  const float* wo = (const float*)d_in[7];
  const float* bo = (const float*)d_in[8];
  float* out = (float*)d_out;

  unsigned short* ws  = (unsigned short*)d_ws;
  unsigned short* qt  = ws;                                 // 8 MB
  unsigned short* kt  = qt + (size_t)BATCH * NN * DIM;      // 8 MB
  unsigned short* vv  = kt + (size_t)BATCH * NN * DIM;      // 8 MB
  unsigned short* o_part = vv + (size_t)BATCH * NN * DIM;   // 16 MB (2 splits)
  float* l_part = (float*)(o_part + (size_t)NSPLIT * BATCH * NN * DIM);  // 256 KB

  hipLaunchKernelGGL(qkv_kernel, dim3(64, 8, 3), dim3(256), 0, stream,
                     x, wq, wk, wv, bq, bk, bv, qt, kt, vv);
  hipLaunchKernelGGL(attn_kernel, dim3(32, 8, NSPLIT), dim3(256), 0, stream,
                     qt, kt, vv, o_part, l_part);
  hipLaunchKernelGGL(outp_kernel, dim3(64, 8), dim3(256), 0, stream,
                     x, wo, bo, o_part, l_part, out);
}